// Round 14
// baseline (369.126 us; speedup 1.0000x reference)
//
#include <hip/hip_runtime.h>

#define NN 100000
#define NE 3200000
#define HID 64
#define NPB 128                         // nodes per bucket (dstlocal = dst & 127)
#define NB  ((NN + NPB - 1) / NPB)      // 782 buckets
#define CHUNK 4096                      // edges per hist/scatter workgroup
#define NCH ((NE + CHUNK - 1) / CHUNK)  // 782 chunks
#define CAP 5632                        // (fallback path only) per-bucket record cap
#define AP 72                           // f16 agg row pitch in halfs (144 B, 16B-aligned)
#define BPITCH 136                      // f16 Bt row pitch in halfs (272 B)

typedef _Float16 half8 __attribute__((ext_vector_type(8)));
typedef float f32x4 __attribute__((ext_vector_type(4)));

__device__ __forceinline__ float h2f(unsigned int u) {
    unsigned short s = (unsigned short)u;
    _Float16 h;
    __builtin_memcpy(&h, &s, 2);
    return (float)h;
}
__device__ __forceinline__ unsigned short f2hb(float v) {
    _Float16 h = (_Float16)v;
    unsigned short s;
    __builtin_memcpy(&s, &h, 2);
    return s;
}

// -------- global histogram over dst buckets --------
__global__ __launch_bounds__(256) void k_hist(const int* __restrict__ dst,
                                              int* __restrict__ ghist) {
    __shared__ int sh[NB];
    for (int j = threadIdx.x; j < NB; j += 256) sh[j] = 0;
    __syncthreads();
    const long long b0 = (long long)blockIdx.x * CHUNK;
    #pragma unroll
    for (int k = 0; k < CHUNK / 256; ++k) {
        long long e = b0 + k * 256 + threadIdx.x;
        if (e < NE) atomicAdd(&sh[dst[e] >> 7], 1);
    }
    __syncthreads();
    for (int j = threadIdx.x; j < NB; j += 256) {
        int c = sh[j];
        if (c) atomicAdd(&ghist[j], c);
    }
}

// -------- exclusive scan of NB bucket counts (single WG) --------
__global__ void k_scan(const int* __restrict__ ghist, int* __restrict__ gbase,
                       int* __restrict__ gcur) {
    __shared__ int sh[1024];
    const int tid = threadIdx.x;
    int v = (tid < NB) ? ghist[tid] : 0;
    sh[tid] = v;
    __syncthreads();
    #pragma unroll
    for (int off = 1; off < 1024; off <<= 1) {
        int t = (tid >= off) ? sh[tid - off] : 0;
        __syncthreads();
        sh[tid] += t;
        __syncthreads();
    }
    if (tid < NB) {
        int b = sh[tid] - v;
        gbase[tid] = b;
        gcur[tid] = b;
    }
}

// -------- de-staged bucketed scatter: count, reserve, re-read + write --------
// LDS only 6.3 KB -> 8 blocks/CU (R13's 46 KB staging capped at 3)
__global__ __launch_bounds__(256) void k_scatter(const int* __restrict__ src,
                                                 const int* __restrict__ dst,
                                                 const float* __restrict__ ew,
                                                 int* __restrict__ gcur,
                                                 int2* __restrict__ rec) {
    __shared__ int sh_cnt[NB];
    __shared__ int sh_base[NB];
    for (int j = threadIdx.x; j < NB; j += 256) sh_cnt[j] = 0;
    __syncthreads();
    const long long b0 = (long long)blockIdx.x * CHUNK;
    #pragma unroll
    for (int k = 0; k < CHUNK / 256; ++k) {
        long long e = b0 + k * 256 + threadIdx.x;
        if (e < NE) atomicAdd(&sh_cnt[dst[e] >> 7], 1);
    }
    __syncthreads();
    for (int j = threadIdx.x; j < NB; j += 256) {
        int c = sh_cnt[j];
        sh_base[j] = c ? atomicAdd(&gcur[j], c) : 0;
        sh_cnt[j] = 0;                                  // reuse as running offset
    }
    __syncthreads();
    #pragma unroll
    for (int k = 0; k < CHUNK / 256; ++k) {
        long long e = b0 + k * 256 + threadIdx.x;
        if (e < NE) {
            int d = dst[e];                             // L1-hot (read in phase 1)
            int b = d >> 7;
            int off = atomicAdd(&sh_cnt[b], 1);
            rec[sh_base[b] + off] = make_int2(src[e] | ((d & 127) << 20),
                                              __float_as_int(ew[e]));
        }
    }
}

// -------- bucketed s1: sx[i] = (s1[i], x[i])  (R8-proven) --------
__global__ __launch_bounds__(256) void k_s1(const int* __restrict__ gbase,
                                            const int* __restrict__ ghist,
                                            const int2* __restrict__ rec,
                                            const float* __restrict__ x,
                                            float2* __restrict__ sx) {
    __shared__ float loc[NPB];
    if (threadIdx.x < NPB) loc[threadIdx.x] = 0.f;
    __syncthreads();
    const int b = blockIdx.x;
    const int beg = gbase[b], cnt = ghist[b];
    for (int t = threadIdx.x; t < cnt; t += 256) {
        int2 rc = rec[beg + t];
        atomicAdd(&loc[rc.x >> 20], __int_as_float(rc.y) * x[rc.x & 0xFFFFF]);
    }
    __syncthreads();
    int i = b * NPB + threadIdx.x;
    if (threadIdx.x < NPB && i < NN) sx[i] = make_float2(loc[threadIdx.x], x[i]);
}

// -------- sort2: dl-hist + scan + direct packed rec2 emit (fuses prep) --------
// No lrec staging: phase 3 re-reads the 33 KB bucket window (L2/L3-hot).
// rec stays unsorted (k_out only needs bucket grouping). LDS 1.5 KB.
__global__ __launch_bounds__(512) void k_sort2(const int* __restrict__ gbase,
                                               const int* __restrict__ ghist,
                                               const int2* __restrict__ rec,
                                               const float2* __restrict__ sx,
                                               int2* __restrict__ rec2,
                                               int* __restrict__ nbase,
                                               int* __restrict__ nend) {
    __shared__ int hist[NPB];
    __shared__ int excl[NPB];
    __shared__ int cur[NPB];
    const int tid = threadIdx.x;
    if (tid < NPB) hist[tid] = 0;
    __syncthreads();
    const int b = blockIdx.x;
    const int beg = gbase[b], cnt = ghist[b];
    for (int t = tid; t < cnt; t += 512)
        atomicAdd(&hist[rec[beg + t].x >> 20], 1);
    __syncthreads();
    if (tid < NPB) excl[tid] = hist[tid];
    __syncthreads();
    #pragma unroll
    for (int off = 1; off < NPB; off <<= 1) {
        int t = (tid < NPB && tid >= off) ? excl[tid - off] : 0;
        __syncthreads();
        if (tid < NPB) excl[tid] += t;
        __syncthreads();
    }
    if (tid < NPB) {
        int e0 = excl[tid] - hist[tid];         // exclusive
        cur[tid] = e0;
        int i = b * NPB + tid;
        if (i < NN) {
            nbase[i] = beg + e0;
            nend[i]  = beg + e0 + hist[tid];
        }
    }
    __syncthreads();
    for (int t = tid; t < cnt; t += 512) {
        int2 rc = rec[beg + t];                 // L2-hot re-read
        const int s = rc.x & 0xFFFFF;
        const int dl = rc.x >> 20;
        const float w = __int_as_float(rc.y);
        const float2 v = sx[s];                 // per-lane gather, L2-resident
        int pos = atomicAdd(&cur[dl], 1);
        rec2[beg + pos] = make_int2((int)f2hb(w * v.x) | ((int)f2hb(w * v.y) << 16),
                                    (int)f2hb(w) | (dl << 16));
    }
}

// -------- mega: byte-identical to R13 (87 us, VALU 64%) --------
__global__ __launch_bounds__(512) void k_mega(
        const int* __restrict__ nbase, const int* __restrict__ nend,
        const int2* __restrict__ rec2, const float2* __restrict__ sx,
        const float* __restrict__ W1_rel, const float* __restrict__ W1_root,
        const float* __restrict__ b1,
        const float* __restrict__ W2_rel, const float* __restrict__ b2,
        const float* __restrict__ W2_root,
        const float* __restrict__ W3_rel, const float* __restrict__ W3_root,
        float* __restrict__ p, float* __restrict__ r) {
    __shared__ _Float16 aggh[NPB * AP];       // 18432 B
    __shared__ _Float16 Bt[HID * BPITCH];     // 17408 B
    __shared__ float2 sxl[NPB];               // 1024 B -> 36.9 KB
    const int tid = threadIdx.x;
    const int f = tid & 63;
    const int wv = tid >> 6;                  // 0..7
    const int gi0 = blockIdx.x * NPB;

    for (int j = tid; j < NPB * AP / 2; j += 512) ((int*)aggh)[j] = 0;
    for (int idx = tid; idx < HID * HID; idx += 512) {
        int k = idx >> 6, n = idx & 63;
        Bt[n * BPITCH + k]       = (_Float16)W2_rel[idx];
        Bt[n * BPITCH + HID + k] = (_Float16)W2_root[idx];
    }
    if (tid < NPB) {
        int gi = gi0 + tid;
        sxl[tid] = (gi < NN) ? sx[gi] : make_float2(0.f, 0.f);
    }
    const float w1r = W1_rel[f], w1t = W1_root[f], b1f = b1[f];
    __syncthreads();

    {
        const int first = gi0 + wv * 16;
        int e = 0, eend = 0;
        if (first < NN) {
            e = nbase[first];
            eend = nend[min(first + 15, NN - 1)];
        }
        int curn = -1;
        float a0 = 0.f, a1 = 0.f, a2 = 0.f, a3 = 0.f;

#define PROC(QQ, AA)                                                              \
        {                                                                         \
            const int dl_ = (QQ).y >> 16;                                         \
            if (dl_ != curn) {                                                    \
                if (curn >= 0) aggh[curn * AP + f] = (_Float16)((a0 + a1) + (a2 + a3)); \
                curn = dl_; a0 = a1 = a2 = a3 = 0.f;                              \
            }                                                                     \
            const float ws_ = h2f((QQ).x & 0xFFFF);                               \
            const float wx_ = h2f(((unsigned)(QQ).x) >> 16);                      \
            const float wf_ = h2f((QQ).y & 0xFFFF);                               \
            AA += fmaxf(0.f, fmaf(ws_, w1r, fmaf(wx_, w1t, wf_ * b1f)));          \
        }

        int2 q0, q1, q2, q3, q4, q5, q6, q7;
        bool have = (e + 8 <= eend);
        if (have) {
            q0 = rec2[e];     q1 = rec2[e + 1]; q2 = rec2[e + 2]; q3 = rec2[e + 3];
            q4 = rec2[e + 4]; q5 = rec2[e + 5]; q6 = rec2[e + 6]; q7 = rec2[e + 7];
        }
        while (have) {
            int2 n0, n1, n2, n3, n4, n5, n6, n7;
            const bool nxt = (e + 16 <= eend);
            if (nxt) {
                n0 = rec2[e + 8];  n1 = rec2[e + 9];  n2 = rec2[e + 10]; n3 = rec2[e + 11];
                n4 = rec2[e + 12]; n5 = rec2[e + 13]; n6 = rec2[e + 14]; n7 = rec2[e + 15];
            }
            PROC(q0, a0) PROC(q1, a1) PROC(q2, a2) PROC(q3, a3)
            PROC(q4, a0) PROC(q5, a1) PROC(q6, a2) PROC(q7, a3)
            e += 8;
            have = nxt;
            if (nxt) {
                q0 = n0; q1 = n1; q2 = n2; q3 = n3;
                q4 = n4; q5 = n5; q6 = n6; q7 = n7;
            }
        }
        for (; e < eend; ++e) {
            int2 qq = rec2[e];
            PROC(qq, a0)
        }
        if (curn >= 0) aggh[curn * AP + f] = (_Float16)((a0 + a1) + (a2 + a3));
#undef PROC
    }
    __syncthreads();

    const int m16 = tid & 15;
    const int quad = (tid & 63) >> 4;
    f32x4 acc[4];
    #pragma unroll
    for (int c_ = 0; c_ < 4; ++c_) acc[c_] = (f32x4){0.f, 0.f, 0.f, 0.f};

    const float2 sm = sxl[wv * 16 + m16];

    #pragma unroll
    for (int kt = 0; kt < 4; ++kt) {
        const int kk = kt * 32;
        half8 a0;
        if (kt < 2) {
            a0 = *(const half8*)&aggh[(wv * 16 + m16) * AP + kk + quad * 8];
        } else {
            const int fk0 = (kt - 2) * 32 + quad * 8;
            #pragma unroll
            for (int j = 0; j < 8; ++j) {
                const float wr = W1_rel[fk0 + j], wt = W1_root[fk0 + j], bb = b1[fk0 + j];
                a0[j] = (_Float16)fmaxf(0.f, fmaf(sm.x, wr, fmaf(sm.y, wt, bb)));
            }
        }
        #pragma unroll
        for (int ct = 0; ct < 4; ++ct) {
            const half8 bfrag = *(const half8*)&Bt[(ct * 16 + m16) * BPITCH + kk + quad * 8];
            acc[ct] = __builtin_amdgcn_mfma_f32_16x16x32_f16(a0, bfrag, acc[ct], 0, 0, 0);
        }
    }

    float b2c[4], w3rc[4], w3tc[4];
    #pragma unroll
    for (int ct = 0; ct < 4; ++ct) {
        const int col = ct * 16 + m16;
        b2c[ct] = b2[col]; w3rc[ct] = W3_rel[col]; w3tc[ct] = W3_root[col];
    }
    float pv[4] = {0.f, 0.f, 0.f, 0.f}, rv[4] = {0.f, 0.f, 0.f, 0.f};
    #pragma unroll
    for (int ct = 0; ct < 4; ++ct) {
        #pragma unroll
        for (int reg = 0; reg < 4; ++reg) {
            const float h2 = fmaxf(0.f, acc[ct][reg] + b2c[ct]);
            pv[reg] = fmaf(h2, w3rc[ct], pv[reg]);
            rv[reg] = fmaf(h2, w3tc[ct], rv[reg]);
        }
    }
    #pragma unroll
    for (int reg = 0; reg < 4; ++reg) {
        #pragma unroll
        for (int msk = 1; msk < 16; msk <<= 1) {
            pv[reg] += __shfl_xor(pv[reg], msk, 64);
            rv[reg] += __shfl_xor(rv[reg], msk, 64);
        }
    }
    if (m16 == 0) {
        #pragma unroll
        for (int reg = 0; reg < 4; ++reg) {
            const int gi = gi0 + wv * 16 + quad * 4 + reg;
            if (gi < NN) { p[gi] = pv[reg]; r[gi] = rv[reg]; }
        }
    }
}

// -------- bucketed output (works on unsorted rec): out = seg_sum + r + b3 --------
__global__ __launch_bounds__(512) void k_out(const int* __restrict__ gbase,
                                             const int* __restrict__ ghist,
                                             const int2* __restrict__ rec,
                                             const float* __restrict__ pp,
                                             const float* __restrict__ rr,
                                             const float* __restrict__ b3,
                                             float* __restrict__ out) {
    __shared__ float loc[NPB];
    if (threadIdx.x < NPB) loc[threadIdx.x] = 0.f;
    __syncthreads();
    const int b = blockIdx.x;
    const int beg = gbase[b], cnt = ghist[b];
    for (int t = threadIdx.x; t < cnt; t += 512) {
        int2 rc = rec[beg + t];
        atomicAdd(&loc[rc.x >> 20], __int_as_float(rc.y) * pp[rc.x & 0xFFFFF]);
    }
    __syncthreads();
    int i = b * NPB + threadIdx.x;
    if (threadIdx.x < NPB && i < NN) out[i] = loc[threadIdx.x] + rr[i] + b3[0];
}

// ======== fallback path (ws too small for separate rec2) — R13-proven ========
__global__ __launch_bounds__(256) void k_sort_fb(const int* __restrict__ gbase,
                                                 const int* __restrict__ ghist,
                                                 int2* __restrict__ rec,
                                                 const float* __restrict__ x,
                                                 float2* __restrict__ sx,
                                                 int* __restrict__ nbase,
                                                 int* __restrict__ nend) {
    __shared__ int2 lrec[CAP];
    __shared__ int hist[NPB];
    __shared__ int excl[NPB];
    __shared__ int cur[NPB];
    __shared__ float loc[NPB];
    const int tid = threadIdx.x;
    if (tid < NPB) { hist[tid] = 0; loc[tid] = 0.f; }
    __syncthreads();
    const int b = blockIdx.x;
    const int beg = gbase[b];
    const int cnt = min(ghist[b], CAP);
    for (int t = tid; t < cnt; t += 256) {
        int2 rc = rec[beg + t];
        lrec[t] = rc;
        int dl = rc.x >> 20;
        atomicAdd(&hist[dl], 1);
        atomicAdd(&loc[dl], __int_as_float(rc.y) * x[rc.x & 0xFFFFF]);
    }
    __syncthreads();
    if (tid < NPB) excl[tid] = hist[tid];
    __syncthreads();
    #pragma unroll
    for (int off = 1; off < NPB; off <<= 1) {
        int t = (tid < NPB && tid >= off) ? excl[tid - off] : 0;
        __syncthreads();
        if (tid < NPB) excl[tid] += t;
        __syncthreads();
    }
    if (tid < NPB) {
        int e0 = excl[tid] - hist[tid];
        cur[tid] = e0;
        int i = b * NPB + tid;
        if (i < NN) {
            nbase[i] = beg + e0;
            nend[i]  = beg + e0 + hist[tid];
            sx[i] = make_float2(loc[tid], x[i]);
        }
    }
    __syncthreads();
    for (int t = tid; t < cnt; t += 256) {
        int2 rc = lrec[t];
        int pos = atomicAdd(&cur[rc.x >> 20], 1);
        rec[beg + pos] = rc;
    }
}
__global__ __launch_bounds__(256) void k_prep_fb(const int2* __restrict__ rec,
                                                 const float2* __restrict__ sx,
                                                 int2* __restrict__ rec2) {
    const int e = blockIdx.x * 256 + threadIdx.x;
    int2 rc = rec[e];
    const int s = rc.x & 0xFFFFF;
    const int dl = rc.x >> 20;
    const float w = __int_as_float(rc.y);
    const float2 v = sx[s];
    rec2[e] = make_int2((int)f2hb(w * v.x) | ((int)f2hb(w * v.y) << 16),
                        (int)f2hb(w) | (dl << 16));
}
__global__ void k_final_atomic(const int* __restrict__ src, const int* __restrict__ dst,
                               const float* __restrict__ ew, const float* __restrict__ pp,
                               float* __restrict__ s3) {
    int e = blockIdx.x * blockDim.x + threadIdx.x;
    if (e < NE) atomicAdd(&s3[dst[e]], ew[e] * pp[src[e]]);
}
__global__ void k_finalize(const float* __restrict__ s3, const float* __restrict__ rr,
                           const float* __restrict__ b3, float* __restrict__ out) {
    int i = blockIdx.x * blockDim.x + threadIdx.x;
    if (i < NN) out[i] = s3[i] + rr[i] + b3[0];
}

extern "C" void kernel_launch(void* const* d_in, const int* in_sizes, int n_in,
                              void* d_out, int out_size, void* d_ws, size_t ws_size,
                              hipStream_t stream) {
    const float* x       = (const float*)d_in[0];
    const int*   ei      = (const int*)  d_in[1];
    const float* ew      = (const float*)d_in[2];
    const float* W1_rel  = (const float*)d_in[3];
    const float* b1      = (const float*)d_in[4];
    const float* W1_root = (const float*)d_in[5];
    const float* W2_rel  = (const float*)d_in[6];
    const float* b2      = (const float*)d_in[7];
    const float* W2_root = (const float*)d_in[8];
    const float* W3_rel  = (const float*)d_in[9];
    const float* b3      = (const float*)d_in[10];
    const float* W3_root = (const float*)d_in[11];

    const int* src = ei;
    const int* dst = ei + NE;

    int2*   rec   = (int2*)d_ws;
    float2* sx    = (float2*)((int*)d_ws + 2 * (size_t)NE);
    float*  p     = (float*)(sx + NN);
    float*  r     = p + NN;
    int*    nbase = (int*)(r + NN);
    int*    nend  = nbase + NN;
    int*    ghist = nend + NN;
    int*    gbase = ghist + NB;
    int*    gcur  = gbase + NB;
    int*    tail  = gcur + NB;
    size_t  off   = ((size_t)((char*)tail - (char*)d_ws) + 7) & ~(size_t)7;
    int2*   rec2  = (int2*)((char*)d_ws + off);
    const size_t needed = off + (size_t)NE * 8;
    const bool big = (ws_size >= needed);
    if (!big) rec2 = rec;

    hipMemsetAsync(ghist, 0, NB * sizeof(int), stream);

    k_hist<<<NCH, 256, 0, stream>>>(dst, ghist);
    k_scan<<<1, 1024, 0, stream>>>(ghist, gbase, gcur);
    k_scatter<<<NCH, 256, 0, stream>>>(src, dst, ew, gcur, rec);

    if (big) {
        k_s1<<<NB, 256, 0, stream>>>(gbase, ghist, rec, x, sx);
        k_sort2<<<NB, 512, 0, stream>>>(gbase, ghist, rec, sx, rec2, nbase, nend);
        k_mega<<<NB, 512, 0, stream>>>(nbase, nend, rec2, sx,
                                       W1_rel, W1_root, b1,
                                       W2_rel, b2, W2_root,
                                       W3_rel, W3_root, p, r);
        k_out<<<NB, 512, 0, stream>>>(gbase, ghist, rec, p, r, b3, (float*)d_out);
    } else {
        k_sort_fb<<<NB, 256, 0, stream>>>(gbase, ghist, rec, x, sx, nbase, nend);
        k_prep_fb<<<NE / 256, 256, 0, stream>>>(rec, sx, rec2);
        k_mega<<<NB, 512, 0, stream>>>(nbase, nend, rec2, sx,
                                       W1_rel, W1_root, b1,
                                       W2_rel, b2, W2_root,
                                       W3_rel, W3_root, p, r);
        float* s3 = (float*)nbase;
        hipMemsetAsync(s3, 0, (size_t)NN * sizeof(float), stream);
        k_final_atomic<<<(NE + 255) / 256, 256, 0, stream>>>(src, dst, ew, p, s3);
        k_finalize<<<(NN + 255) / 256, 256, 0, stream>>>(s3, r, b3, (float*)d_out);
    }
}

// Round 15
// 326.753 us; speedup vs baseline: 1.1297x; 1.1297x over previous
//
#include <hip/hip_runtime.h>

#define NN 100000
#define NE 3200000
#define HID 64
#define NPB 256                         // nodes per bucket (dl = dst & 255, 8 bits)
#define NB  ((NN + NPB - 1) / NPB)      // 391 buckets
#define MNP 128                         // nodes per k_mega window
#define NMW ((NN + MNP - 1) / MNP)      // 782 mega windows
#define CHUNK 4096                      // edges per hist/scatter workgroup
#define NCH ((NE + CHUNK - 1) / CHUNK)  // 782 chunks
#define AP 72                           // f16 agg row pitch in halfs (144 B, 16B-aligned)
#define BPITCH 136                      // f16 Bt row pitch in halfs (272 B)
#define SRCM 0x1FFFF                    // src mask (17 bits; NN < 2^17)

typedef _Float16 half8 __attribute__((ext_vector_type(8)));
typedef float f32x4 __attribute__((ext_vector_type(4)));

__device__ __forceinline__ float h2f(unsigned int u) {
    unsigned short s = (unsigned short)u;
    _Float16 h;
    __builtin_memcpy(&h, &s, 2);
    return (float)h;
}
__device__ __forceinline__ unsigned short f2hb(float v) {
    _Float16 h = (_Float16)v;
    unsigned short s;
    __builtin_memcpy(&s, &h, 2);
    return s;
}

// -------- global histogram over dst buckets --------
__global__ __launch_bounds__(256) void k_hist(const int* __restrict__ dst,
                                              int* __restrict__ ghist) {
    __shared__ int sh[NB];
    for (int j = threadIdx.x; j < NB; j += 256) sh[j] = 0;
    __syncthreads();
    const long long b0 = (long long)blockIdx.x * CHUNK;
    #pragma unroll
    for (int k = 0; k < CHUNK / 256; ++k) {
        long long e = b0 + k * 256 + threadIdx.x;
        if (e < NE) atomicAdd(&sh[dst[e] >> 8], 1);
    }
    __syncthreads();
    for (int j = threadIdx.x; j < NB; j += 256) {
        int c = sh[j];
        if (c) atomicAdd(&ghist[j], c);
    }
}

// -------- exclusive scan of NB bucket counts (single WG, 512 thr) --------
__global__ __launch_bounds__(512) void k_scan(const int* __restrict__ ghist,
                                              int* __restrict__ gbase,
                                              int* __restrict__ gcur) {
    __shared__ int sh[512];
    const int tid = threadIdx.x;
    int v = (tid < NB) ? ghist[tid] : 0;
    sh[tid] = v;
    __syncthreads();
    #pragma unroll
    for (int off = 1; off < 512; off <<= 1) {
        int t = (tid >= off) ? sh[tid - off] : 0;
        __syncthreads();
        sh[tid] += t;
        __syncthreads();
    }
    if (tid < NB) {
        int b = sh[tid] - v;
        gbase[tid] = b;
        gcur[tid] = b;
    }
}

// -------- scatter with in-LDS counting sort -> bucket-grouped coalesced emission ----
__global__ __launch_bounds__(256) void k_scatter(const int* __restrict__ src,
                                                 const int* __restrict__ dst,
                                                 const float* __restrict__ ew,
                                                 int* __restrict__ gcur,
                                                 int2* __restrict__ rec) {
    __shared__ int2 lrec[CHUNK];              // 32 KB
    __shared__ unsigned short lb[CHUNK];      // 8 KB  (bucket id per record)
    __shared__ unsigned short sidx[CHUNK];    // 8 KB  (sorted-order -> record idx)
    __shared__ int cnt[NB];                   // counts, then reused as cursor
    __shared__ int excl[NB];
    __shared__ int base[NB];
    __shared__ int sc[512];
    const int tid = threadIdx.x;
    for (int j = tid; j < NB; j += 256) cnt[j] = 0;
    __syncthreads();
    const long long b0 = (long long)blockIdx.x * CHUNK;
    const int valid = (int)min((long long)CHUNK, (long long)NE - b0);
    #pragma unroll
    for (int k = 0; k < CHUNK / 256; ++k) {
        int idx = k * 256 + tid;
        if (idx < valid) {
            long long e = b0 + idx;
            int d = dst[e];
            int b = d >> 8;
            lrec[idx] = make_int2(src[e] | ((d & 255) << 17), __float_as_int(ew[e]));
            lb[idx] = (unsigned short)b;
            atomicAdd(&cnt[b], 1);
        }
    }
    __syncthreads();
    // inclusive scan of counts (512-slot Hillis-Steele, NB=391 padded)
    {
        int v = (tid < NB) ? cnt[tid] : 0;
        sc[tid + 256] = 0;                    // lanes 256..511 covered below
        sc[tid] = v;
        // need 512 slots with only 256 threads: handle two slots per thread
        int v2 = (tid + 256 < NB) ? cnt[tid + 256] : 0;
        sc[tid + 256] = v2;
        __syncthreads();
        #pragma unroll
        for (int off = 1; off < 512; off <<= 1) {
            int a0 = (tid >= off) ? sc[tid - off] : 0;
            int a1 = (tid + 256 >= off) ? sc[tid + 256 - off] : 0;
            __syncthreads();
            sc[tid] += a0;
            sc[tid + 256] += a1;
            __syncthreads();
        }
        if (tid < NB) excl[tid] = sc[tid] - cnt[tid];
        if (tid + 256 < NB) excl[tid + 256] = sc[tid + 256] - cnt[tid + 256];
    }
    __syncthreads();
    // global reservation + init cursor to local exclusive offset
    for (int j = tid; j < NB; j += 256) {
        int c = cnt[j];
        base[j] = c ? atomicAdd(&gcur[j], c) : 0;
        cnt[j] = excl[j];                     // cursor
    }
    __syncthreads();
    // placement: sorted position per record
    #pragma unroll
    for (int k = 0; k < CHUNK / 256; ++k) {
        int idx = k * 256 + tid;
        if (idx < valid) {
            int sp = atomicAdd(&cnt[lb[idx]], 1);
            sidx[sp] = (unsigned short)idx;
        }
    }
    __syncthreads();
    // emission in bucket order: consecutive lanes -> consecutive addresses per run
    #pragma unroll
    for (int k = 0; k < CHUNK / 256; ++k) {
        int sp = k * 256 + tid;
        if (sp < valid) {
            int idx = sidx[sp];
            int b = lb[idx];
            rec[base[b] + (sp - excl[b])] = lrec[idx];
        }
    }
}

// -------- bucketed s1: sx[i] = (s1[i], x[i]) --------
__global__ __launch_bounds__(512) void k_s1(const int* __restrict__ gbase,
                                            const int* __restrict__ ghist,
                                            const int2* __restrict__ rec,
                                            const float* __restrict__ x,
                                            float2* __restrict__ sx) {
    __shared__ float loc[NPB];
    if (threadIdx.x < NPB) loc[threadIdx.x] = 0.f;
    __syncthreads();
    const int b = blockIdx.x;
    const int beg = gbase[b], cnt = ghist[b];
    for (int t = threadIdx.x; t < cnt; t += 512) {
        int2 rc = rec[beg + t];
        atomicAdd(&loc[rc.x >> 17], __int_as_float(rc.y) * x[rc.x & SRCM]);
    }
    __syncthreads();
    int i = b * NPB + threadIdx.x;
    if (threadIdx.x < NPB && i < NN) sx[i] = make_float2(loc[threadIdx.x], x[i]);
}

// -------- sort2: dl-hist + scan + direct packed rec2 emit (fused prep) --------
__global__ __launch_bounds__(512) void k_sort2(const int* __restrict__ gbase,
                                               const int* __restrict__ ghist,
                                               const int2* __restrict__ rec,
                                               const float2* __restrict__ sx,
                                               int2* __restrict__ rec2,
                                               int* __restrict__ nbase,
                                               int* __restrict__ nend) {
    __shared__ int hist[NPB];
    __shared__ int excl[NPB];
    __shared__ int cur[NPB];
    const int tid = threadIdx.x;
    if (tid < NPB) hist[tid] = 0;
    __syncthreads();
    const int b = blockIdx.x;
    const int beg = gbase[b], cnt = ghist[b];
    for (int t = tid; t < cnt; t += 512)
        atomicAdd(&hist[rec[beg + t].x >> 17], 1);
    __syncthreads();
    if (tid < NPB) excl[tid] = hist[tid];
    __syncthreads();
    #pragma unroll
    for (int off = 1; off < NPB; off <<= 1) {
        int t = (tid < NPB && tid >= off) ? excl[tid - off] : 0;
        __syncthreads();
        if (tid < NPB) excl[tid] += t;
        __syncthreads();
    }
    if (tid < NPB) {
        int e0 = excl[tid] - hist[tid];
        cur[tid] = e0;
        int i = b * NPB + tid;
        if (i < NN) {
            nbase[i] = beg + e0;
            nend[i]  = beg + e0 + hist[tid];
        }
    }
    __syncthreads();
    for (int t = tid; t < cnt; t += 512) {
        int2 rc = rec[beg + t];                 // L2-hot re-read
        const int s = rc.x & SRCM;
        const int dl = rc.x >> 17;
        const float w = __int_as_float(rc.y);
        const float2 v = sx[s];                 // per-lane gather, L2-resident
        int pos = atomicAdd(&cur[dl], 1);
        rec2[beg + pos] = make_int2((int)f2hb(w * v.x) | ((int)f2hb(w * v.y) << 16),
                                    (int)f2hb(w) | (dl << 16));
    }
}

// -------- mega: 128-node windows, gather-free streaming + MFMA (R13-proven) --------
__global__ __launch_bounds__(512) void k_mega(
        const int* __restrict__ nbase, const int* __restrict__ nend,
        const int2* __restrict__ rec2, const float2* __restrict__ sx,
        const float* __restrict__ W1_rel, const float* __restrict__ W1_root,
        const float* __restrict__ b1,
        const float* __restrict__ W2_rel, const float* __restrict__ b2,
        const float* __restrict__ W2_root,
        const float* __restrict__ W3_rel, const float* __restrict__ W3_root,
        float* __restrict__ p, float* __restrict__ r) {
    __shared__ _Float16 aggh[MNP * AP];       // 18432 B
    __shared__ _Float16 Bt[HID * BPITCH];     // 17408 B
    __shared__ float2 sxl[MNP];               // 1024 B -> 36.9 KB
    const int tid = threadIdx.x;
    const int f = tid & 63;
    const int wv = tid >> 6;                  // 0..7
    const int gi0 = blockIdx.x * MNP;

    for (int j = tid; j < MNP * AP / 2; j += 512) ((int*)aggh)[j] = 0;
    for (int idx = tid; idx < HID * HID; idx += 512) {
        int k = idx >> 6, n = idx & 63;
        Bt[n * BPITCH + k]       = (_Float16)W2_rel[idx];
        Bt[n * BPITCH + HID + k] = (_Float16)W2_root[idx];
    }
    if (tid < MNP) {
        int gi = gi0 + tid;
        sxl[tid] = (gi < NN) ? sx[gi] : make_float2(0.f, 0.f);
    }
    const float w1r = W1_rel[f], w1t = W1_root[f], b1f = b1[f];
    __syncthreads();

    {
        const int first = gi0 + wv * 16;
        int e = 0, eend = 0;
        if (first < NN) {
            e = nbase[first];
            eend = nend[min(first + 15, NN - 1)];
        }
        int curn = -1;
        float a0 = 0.f, a1 = 0.f, a2 = 0.f, a3 = 0.f;

// window-local row = dl & 127 (window = half bucket; all its records share dl bit 7)
#define PROC(QQ, AA)                                                              \
        {                                                                         \
            const int dl_ = (QQ).y >> 16;                                         \
            if (dl_ != curn) {                                                    \
                if (curn >= 0) aggh[(curn & 127) * AP + f] = (_Float16)((a0 + a1) + (a2 + a3)); \
                curn = dl_; a0 = a1 = a2 = a3 = 0.f;                              \
            }                                                                     \
            const float ws_ = h2f((QQ).x & 0xFFFF);                               \
            const float wx_ = h2f(((unsigned)(QQ).x) >> 16);                      \
            const float wf_ = h2f((QQ).y & 0xFFFF);                               \
            AA += fmaxf(0.f, fmaf(ws_, w1r, fmaf(wx_, w1t, wf_ * b1f)));          \
        }

        int2 q0, q1, q2, q3, q4, q5, q6, q7;
        bool have = (e + 8 <= eend);
        if (have) {
            q0 = rec2[e];     q1 = rec2[e + 1]; q2 = rec2[e + 2]; q3 = rec2[e + 3];
            q4 = rec2[e + 4]; q5 = rec2[e + 5]; q6 = rec2[e + 6]; q7 = rec2[e + 7];
        }
        while (have) {
            int2 n0, n1, n2, n3, n4, n5, n6, n7;
            const bool nxt = (e + 16 <= eend);
            if (nxt) {
                n0 = rec2[e + 8];  n1 = rec2[e + 9];  n2 = rec2[e + 10]; n3 = rec2[e + 11];
                n4 = rec2[e + 12]; n5 = rec2[e + 13]; n6 = rec2[e + 14]; n7 = rec2[e + 15];
            }
            PROC(q0, a0) PROC(q1, a1) PROC(q2, a2) PROC(q3, a3)
            PROC(q4, a0) PROC(q5, a1) PROC(q6, a2) PROC(q7, a3)
            e += 8;
            have = nxt;
            if (nxt) {
                q0 = n0; q1 = n1; q2 = n2; q3 = n3;
                q4 = n4; q5 = n5; q6 = n6; q7 = n7;
            }
        }
        for (; e < eend; ++e) {
            int2 qq = rec2[e];
            PROC(qq, a0)
        }
        if (curn >= 0) aggh[(curn & 127) * AP + f] = (_Float16)((a0 + a1) + (a2 + a3));
#undef PROC
    }
    __syncthreads();

    const int m16 = tid & 15;
    const int quad = (tid & 63) >> 4;
    f32x4 acc[4];
    #pragma unroll
    for (int c_ = 0; c_ < 4; ++c_) acc[c_] = (f32x4){0.f, 0.f, 0.f, 0.f};

    const float2 sm = sxl[wv * 16 + m16];

    #pragma unroll
    for (int kt = 0; kt < 4; ++kt) {
        const int kk = kt * 32;
        half8 a0;
        if (kt < 2) {
            a0 = *(const half8*)&aggh[(wv * 16 + m16) * AP + kk + quad * 8];
        } else {
            const int fk0 = (kt - 2) * 32 + quad * 8;
            #pragma unroll
            for (int j = 0; j < 8; ++j) {
                const float wr = W1_rel[fk0 + j], wt = W1_root[fk0 + j], bb = b1[fk0 + j];
                a0[j] = (_Float16)fmaxf(0.f, fmaf(sm.x, wr, fmaf(sm.y, wt, bb)));
            }
        }
        #pragma unroll
        for (int ct = 0; ct < 4; ++ct) {
            const half8 bfrag = *(const half8*)&Bt[(ct * 16 + m16) * BPITCH + kk + quad * 8];
            acc[ct] = __builtin_amdgcn_mfma_f32_16x16x32_f16(a0, bfrag, acc[ct], 0, 0, 0);
        }
    }

    float b2c[4], w3rc[4], w3tc[4];
    #pragma unroll
    for (int ct = 0; ct < 4; ++ct) {
        const int col = ct * 16 + m16;
        b2c[ct] = b2[col]; w3rc[ct] = W3_rel[col]; w3tc[ct] = W3_root[col];
    }
    float pv[4] = {0.f, 0.f, 0.f, 0.f}, rv[4] = {0.f, 0.f, 0.f, 0.f};
    #pragma unroll
    for (int ct = 0; ct < 4; ++ct) {
        #pragma unroll
        for (int reg = 0; reg < 4; ++reg) {
            const float h2 = fmaxf(0.f, acc[ct][reg] + b2c[ct]);
            pv[reg] = fmaf(h2, w3rc[ct], pv[reg]);
            rv[reg] = fmaf(h2, w3tc[ct], rv[reg]);
        }
    }
    #pragma unroll
    for (int reg = 0; reg < 4; ++reg) {
        #pragma unroll
        for (int msk = 1; msk < 16; msk <<= 1) {
            pv[reg] += __shfl_xor(pv[reg], msk, 64);
            rv[reg] += __shfl_xor(rv[reg], msk, 64);
        }
    }
    if (m16 == 0) {
        #pragma unroll
        for (int reg = 0; reg < 4; ++reg) {
            const int gi = gi0 + wv * 16 + quad * 4 + reg;
            if (gi < NN) { p[gi] = pv[reg]; r[gi] = rv[reg]; }
        }
    }
}

// -------- bucketed output (unsorted rec): out = seg_sum(w * p[src]) + r + b3 --------
__global__ __launch_bounds__(512) void k_out(const int* __restrict__ gbase,
                                             const int* __restrict__ ghist,
                                             const int2* __restrict__ rec,
                                             const float* __restrict__ pp,
                                             const float* __restrict__ rr,
                                             const float* __restrict__ b3,
                                             float* __restrict__ out) {
    __shared__ float loc[NPB];
    if (threadIdx.x < NPB) loc[threadIdx.x] = 0.f;
    __syncthreads();
    const int b = blockIdx.x;
    const int beg = gbase[b], cnt = ghist[b];
    for (int t = threadIdx.x; t < cnt; t += 512) {
        int2 rc = rec[beg + t];
        atomicAdd(&loc[rc.x >> 17], __int_as_float(rc.y) * pp[rc.x & SRCM]);
    }
    __syncthreads();
    int i = b * NPB + threadIdx.x;
    if (threadIdx.x < NPB && i < NN) out[i] = loc[threadIdx.x] + rr[i] + b3[0];
}

extern "C" void kernel_launch(void* const* d_in, const int* in_sizes, int n_in,
                              void* d_out, int out_size, void* d_ws, size_t ws_size,
                              hipStream_t stream) {
    const float* x       = (const float*)d_in[0];
    const int*   ei      = (const int*)  d_in[1];
    const float* ew      = (const float*)d_in[2];
    const float* W1_rel  = (const float*)d_in[3];
    const float* b1      = (const float*)d_in[4];
    const float* W1_root = (const float*)d_in[5];
    const float* W2_rel  = (const float*)d_in[6];
    const float* b2      = (const float*)d_in[7];
    const float* W2_root = (const float*)d_in[8];
    const float* W3_rel  = (const float*)d_in[9];
    const float* b3      = (const float*)d_in[10];
    const float* W3_root = (const float*)d_in[11];

    const int* src = ei;
    const int* dst = ei + NE;

    // ws (~54 MB of the ~268 MB workspace; R11 profile showed ws poison = 268 MB)
    int2*   rec   = (int2*)d_ws;
    float2* sx    = (float2*)((int*)d_ws + 2 * (size_t)NE);
    float*  p     = (float*)(sx + NN);
    float*  r     = p + NN;
    int*    nbase = (int*)(r + NN);
    int*    nend  = nbase + NN;
    int*    ghist = nend + NN;
    int*    gbase = ghist + NB;
    int*    gcur  = gbase + NB;
    int*    tail  = gcur + NB;
    size_t  off   = ((size_t)((char*)tail - (char*)d_ws) + 7) & ~(size_t)7;
    int2*   rec2  = (int2*)((char*)d_ws + off);

    hipMemsetAsync(ghist, 0, NB * sizeof(int), stream);

    k_hist<<<NCH, 256, 0, stream>>>(dst, ghist);
    k_scan<<<1, 512, 0, stream>>>(ghist, gbase, gcur);
    k_scatter<<<NCH, 256, 0, stream>>>(src, dst, ew, gcur, rec);
    k_s1<<<NB, 512, 0, stream>>>(gbase, ghist, rec, x, sx);
    k_sort2<<<NB, 512, 0, stream>>>(gbase, ghist, rec, sx, rec2, nbase, nend);
    k_mega<<<NMW, 512, 0, stream>>>(nbase, nend, rec2, sx,
                                    W1_rel, W1_root, b1,
                                    W2_rel, b2, W2_root,
                                    W3_rel, W3_root, p, r);
    k_out<<<NB, 512, 0, stream>>>(gbase, ghist, rec, p, r, b3, (float*)d_out);
}